// Round 16
// baseline (155.820 us; speedup 1.0000x reference)
//
#include <hip/hip_runtime.h>
#include <math.h>

typedef unsigned short u16;
typedef _Float16 f16;
typedef __attribute__((ext_vector_type(8))) short bf16x8;
typedef __attribute__((ext_vector_type(4))) float f32x4;
typedef __attribute__((ext_vector_type(4))) f16 f16x4;

#define D_MODEL 1024
#define SEQ_N   2048
#define HEADS   16
#define DHEAD   64
#define M3      3072
#define JSPLIT  2
#define JCHUNK  (SEQ_N / JSPLIT)   // 1024
#define NIT     (JCHUNK / 64)      // 16
// Q pre-scale: 0.125 * log2(e); attn then uses exp2(s - 4*log2(e)) == exp(s/8 - 4)
#define QSCALE  0.18033688011112042f
#define EXPOFF  5.770780163555854f

#define GLOBAL_AS __attribute__((address_space(1)))
#define LDS_AS    __attribute__((address_space(3)))
#define ASYNC16(gp, lp) __builtin_amdgcn_global_load_lds( \
    (const GLOBAL_AS unsigned int*)(gp), (LDS_AS unsigned int*)(lp), 16, 0, 0)

__device__ __forceinline__ u16 f2bf(float f) {
  union { float f; unsigned int u; } v; v.f = f;
  unsigned int r = v.u + 0x7fffu + ((v.u >> 16) & 1u);  // RNE
  return (u16)(r >> 16);
}

// ------- prep: blocks [0,256) = LN stage-1 reduce; blocks [256,2304) = weight pack -------
__global__ __launch_bounds__(256) void prep(const float* __restrict__ x,
                                            double* __restrict__ part,
                                            const float* __restrict__ WQ,
                                            const float* __restrict__ WK,
                                            const float* __restrict__ WV,
                                            const float* __restrict__ W0,
                                            u16* __restrict__ Wp,
                                            u16* __restrict__ W0p) {
  __shared__ double ls[256], lss[256];
  __shared__ float tile[32][65];
  int t = threadIdx.x;
  int b = blockIdx.x;
  if (b < 256) {
    const float4* x4 = (const float4*)x;
    const int n4 = (D_MODEL * SEQ_N) / 4;
    double s = 0.0, ss = 0.0;
    for (int idx = b * 256 + t; idx < n4; idx += 256 * 256) {
      float4 v = x4[idx];
      s  += (double)v.x + (double)v.y + (double)v.z + (double)v.w;
      ss += (double)v.x * v.x + (double)v.y * v.y + (double)v.z * v.z + (double)v.w * v.w;
    }
    ls[t] = s; lss[t] = ss;
    __syncthreads();
    for (int off = 128; off > 0; off >>= 1) {
      if (t < off) { ls[t] += ls[t + off]; lss[t] += lss[t + off]; }
      __syncthreads();
    }
    if (t == 0) { part[2 * b] = ls[0]; part[2 * b + 1] = lss[0]; }
    return;
  }
  int f = b - 256;
  int z = f >> 9;
  int rem = f & 511;
  if (z == 3) {
    int idx = rem * 512 + t;
#pragma unroll
    for (int r = 0; r < 2; ++r, idx += 256) {
      float4 v = ((const float4*)W0)[idx];
      unsigned int lo = (unsigned int)f2bf(v.x) | ((unsigned int)f2bf(v.y) << 16);
      unsigned int hi = (unsigned int)f2bf(v.z) | ((unsigned int)f2bf(v.w) << 16);
      uint2 o; o.x = lo; o.y = hi;
      *(uint2*)(&W0p[(size_t)idx * 4]) = o;
    }
    return;
  }
  const float* W = (z == 0) ? WQ : ((z == 1) ? WK : WV);
  int h = rem >> 5, cb = (rem & 31) * 32;
  int dh = t & 63, cl = t >> 6;
  for (int r = 0; r < 8; ++r) {
    int c = cl + r * 4;
    tile[c][dh] = W[((size_t)h * D_MODEL + cb + c) * DHEAD + dh];
  }
  __syncthreads();
  int c2 = t & 31, d2 = t >> 5;
  for (int r = 0; r < 8; ++r) {
    int dd = d2 + r * 8;
    Wp[(size_t)((z * HEADS + h) * DHEAD + dd) * D_MODEL + cb + c2] = f2bf(tile[c2][dd]);
  }
}

// ------- normalize + transpose: x[d,N] -> xn_t[N,d] (bf16); stage-2 reduce fused -------
__global__ __launch_bounds__(256) void ln_norm_t(const float* __restrict__ x,
                                                 const double* __restrict__ part,
                                                 u16* __restrict__ xnt) {
  __shared__ double ls[256], lss[256];
  __shared__ float tile[64][65];
  int t = threadIdx.x;
  ls[t] = part[2 * t]; lss[t] = part[2 * t + 1];
  __syncthreads();
  for (int off = 128; off > 0; off >>= 1) {
    if (t < off) { ls[t] += ls[t + off]; lss[t] += lss[t + off]; }
    __syncthreads();
  }
  double inv = 1.0 / ((double)D_MODEL * (double)SEQ_N);
  double m = ls[0] * inv;
  double vv = lss[0] * inv - m * m;
  float mean = (float)m;
  float rstd = (float)(1.0 / sqrt(vv + 1e-5));

  int ib = blockIdx.x * 64, cb = blockIdx.y * 64;
  int il = t & 63, cl = t >> 6;
  for (int r = 0; r < 16; ++r) {
    int c = cl + r * 4;
    tile[c][il] = (x[(size_t)(cb + c) * SEQ_N + ib + il] - mean) * rstd;
  }
  __syncthreads();
  int c2 = t & 63, i2 = t >> 6;
  for (int r = 0; r < 16; ++r) {
    int i = i2 + r * 4;
    xnt[(size_t)(ib + i) * D_MODEL + cb + c2] = f2bf(tile[c2][i]);
  }
}

// -------- QKV projection GEMM: 96(M)x128(N), BK=64, counted-vmcnt dbuf + T2 swizzle --------
__global__ __launch_bounds__(256) void gemm_qkv(const u16* __restrict__ A,
                                                const u16* __restrict__ Bt,
                                                u16* __restrict__ Qt,
                                                u16* __restrict__ Kt,
                                                f16* __restrict__ Vb) {
  __shared__ __align__(16) u16 Alds[2 * 2 * 96 * 32];
  __shared__ __align__(16) u16 Blds[2 * 2 * 128 * 32];
  int t = threadIdx.x;
  int lane = t & 63, w = t >> 6;
  int g = lane >> 4, l16 = lane & 15;
  int wr = w >> 1, wc = w & 1;
  int flat = blockIdx.x;
  int wi = flat >> 3;
  int wx = wi & 7, wy = wi >> 3;
  int cx = (flat & 7) & 1, cy = (flat & 7) >> 1;
  int bx = cx * 8 + wx;
  int by = cy * 8 + wy;
  int mb = by * 96, nb = bx * 128;

  f32x4 acc[3][4];
#pragma unroll
  for (int i = 0; i < 3; ++i)
#pragma unroll
    for (int j = 0; j < 4; ++j) acc[i][j] = (f32x4){0.f, 0.f, 0.f, 0.f};

  const u16* AgP[3]; int ldsA[3];
#pragma unroll
  for (int r = 0; r < 3; ++r) {
    int idx = r * 256 + t;
    int kk = (idx >= 384) ? 1 : 0;
    int rem = idx - kk * 384;
    int row = rem >> 2, c4 = rem & 3;
    int csw = c4 ^ ((row >> 1) & 3);   // inverse-swizzled source chunk
    AgP[r] = A + (size_t)(mb + row) * D_MODEL + kk * 32 + csw * 8;
    ldsA[r] = idx * 8;                 // LDS dest stays lane-linear
  }
  const u16* BgP[4]; int ldsB[4];
#pragma unroll
  for (int r = 0; r < 4; ++r) {
    int idx = r * 256 + t;
    int kk = idx >> 9;
    int rem = idx & 511;
    int row = rem >> 2, c4 = rem & 3;
    int csw = c4 ^ ((row >> 1) & 3);
    BgP[r] = Bt + (size_t)(nb + row) * D_MODEL + kk * 32 + csw * 8;
    ldsB[r] = idx * 8;
  }

#pragma unroll
  for (int r = 0; r < 3; ++r) ASYNC16(AgP[r], &Alds[ldsA[r]]);
#pragma unroll
  for (int r = 0; r < 4; ++r) ASYNC16(BgP[r], &Blds[ldsB[r]]);
#pragma unroll
  for (int r = 0; r < 3; ++r) ASYNC16(AgP[r] + 64, &Alds[6144 + ldsA[r]]);
#pragma unroll
  for (int r = 0; r < 4; ++r) ASYNC16(BgP[r] + 64, &Blds[8192 + ldsB[r]]);

  int rowa0 = wr * 48, rowb0 = wc * 64;
  int cur = 0;
  for (int ks = 0; ks < 16; ++ks) {
    if (ks < 15) asm volatile("s_waitcnt vmcnt(7)" ::: "memory");
    else         asm volatile("s_waitcnt vmcnt(0)" ::: "memory");
    __builtin_amdgcn_s_barrier();
#pragma unroll
    for (int kk = 0; kk < 2; ++kk) {
      bf16x8 af[3], bf[4];
#pragma unroll
      for (int tm = 0; tm < 3; ++tm) {
        int row = rowa0 + tm * 16 + l16;
        int gs = g ^ ((row >> 1) & 3);   // swizzled read chunk
        af[tm] = *(const bf16x8*)(&Alds[cur * 6144 + kk * 3072 + row * 32 + gs * 8]);
      }
#pragma unroll
      for (int tn = 0; tn < 4; ++tn) {
        int row = rowb0 + tn * 16 + l16;
        int gs = g ^ ((row >> 1) & 3);
        bf[tn] = *(const bf16x8*)(&Blds[cur * 8192 + kk * 4096 + row * 32 + gs * 8]);
      }
#pragma unroll
      for (int tm = 0; tm < 3; ++tm)
#pragma unroll
        for (int tn = 0; tn < 4; ++tn)
          acc[tm][tn] = __builtin_amdgcn_mfma_f32_16x16x32_bf16(af[tm], bf[tn],
                                                                acc[tm][tn], 0, 0, 0);
    }
    __builtin_amdgcn_s_barrier();
    if (ks + 2 < 16) {
      int kb = (ks + 2) * 64;
#pragma unroll
      for (int r = 0; r < 3; ++r) ASYNC16(AgP[r] + kb, &Alds[cur * 6144 + ldsA[r]]);
#pragma unroll
      for (int r = 0; r < 4; ++r) ASYNC16(BgP[r] + kb, &Blds[cur * 8192 + ldsB[r]]);
    }
    cur ^= 1;
  }

#pragma unroll
  for (int tm = 0; tm < 3; ++tm) {
    int row0 = mb + wr * 48 + tm * 16 + g * 4;
#pragma unroll
    for (int tn = 0; tn < 4; ++tn) {
      int col = nb + wc * 64 + tn * 16 + l16;
      if (row0 < 2 * D_MODEL) {
        u16* T = (row0 < D_MODEL) ? Qt : Kt;
        float sc = (row0 < D_MODEL) ? QSCALE : 1.0f;  // pre-scale Q only
        int rbase = (row0 < D_MODEL) ? row0 : row0 - D_MODEL;
        ushort4 o;
        o.x = f2bf(acc[tm][tn][0] * sc); o.y = f2bf(acc[tm][tn][1] * sc);
        o.z = f2bf(acc[tm][tn][2] * sc); o.w = f2bf(acc[tm][tn][3] * sc);
        *(ushort4*)(&T[(size_t)col * D_MODEL + rbase]) = o;
      } else {
        int rbase = row0 - 2 * D_MODEL;
#pragma unroll
        for (int r = 0; r < 4; ++r)
          Vb[(size_t)(rbase + r) * SEQ_N + col] = (f16)acc[tm][tn][r];
      }
    }
  }
}

// ------- out-proj GEMM 64x64, BK=64, counted-vmcnt dbuf + T2 swizzle -------
__global__ __launch_bounds__(256) void gemm_bf16(const u16* __restrict__ A,
                                                 const u16* __restrict__ Bt,
                                                 float* __restrict__ C,
                                                 const float* __restrict__ res,
                                                 int M, int N, int K) {
  __shared__ __align__(16) u16 Alds[2 * 2 * 64 * 32];
  __shared__ __align__(16) u16 Blds[2 * 2 * 64 * 32];
  int t = threadIdx.x;
  int w = t >> 6, lane = t & 63;
  int g = lane >> 4, l16 = lane & 15;
  int flat = blockIdx.x;
  int wi = flat >> 3;
  int wx = wi & 7, wy = wi >> 3;
  int cx = (flat & 7) & 3, cy = (flat & 7) >> 2;
  int bx = cx * 8 + wx;
  int by = cy * 8 + wy;
  int mb = by * 64, nb = bx * 64;
  f32x4 acc[4];
  for (int i = 0; i < 4; ++i) acc[i] = (f32x4){0.f, 0.f, 0.f, 0.f};

  const u16* AgP[2]; const u16* BgP[2]; int ldsO[2];
#pragma unroll
  for (int r = 0; r < 2; ++r) {
    int idx = r * 256 + t;
    int kk = idx >> 8;
    int rem = idx & 255;
    int row = rem >> 2, c4 = rem & 3;
    int csw = c4 ^ ((row >> 1) & 3);
    AgP[r] = A + (size_t)(mb + row) * K + kk * 32 + csw * 8;
    BgP[r] = Bt + (size_t)(nb + row) * K + kk * 32 + csw * 8;
    ldsO[r] = idx * 8;
  }

#pragma unroll
  for (int r = 0; r < 2; ++r) { ASYNC16(AgP[r], &Alds[ldsO[r]]); ASYNC16(BgP[r], &Blds[ldsO[r]]); }
#pragma unroll
  for (int r = 0; r < 2; ++r) {
    ASYNC16(AgP[r] + 64, &Alds[4096 + ldsO[r]]);
    ASYNC16(BgP[r] + 64, &Blds[4096 + ldsO[r]]);
  }

  int cur = 0;
  const int NK = 16;
  for (int ks = 0; ks < NK; ++ks) {
    if (ks < NK - 1) asm volatile("s_waitcnt vmcnt(4)" ::: "memory");
    else             asm volatile("s_waitcnt vmcnt(0)" ::: "memory");
    __builtin_amdgcn_s_barrier();
#pragma unroll
    for (int kk = 0; kk < 2; ++kk) {
      int rowa = w * 16 + l16;
      int gsa = g ^ ((rowa >> 1) & 3);
      bf16x8 af = *(const bf16x8*)(&Alds[cur * 4096 + kk * 2048 + rowa * 32 + gsa * 8]);
#pragma unroll
      for (int tn = 0; tn < 4; ++tn) {
        int rowb = tn * 16 + l16;
        int gsb = g ^ ((rowb >> 1) & 3);
        bf16x8 bf = *(const bf16x8*)(&Blds[cur * 4096 + kk * 2048 + rowb * 32 + gsb * 8]);
        acc[tn] = __builtin_amdgcn_mfma_f32_16x16x32_bf16(af, bf, acc[tn], 0, 0, 0);
      }
    }
    __builtin_amdgcn_s_barrier();
    if (ks + 2 < NK) {
      int kb = (ks + 2) * 64;
#pragma unroll
      for (int r = 0; r < 2; ++r) {
        ASYNC16(AgP[r] + kb, &Alds[cur * 4096 + ldsO[r]]);
        ASYNC16(BgP[r] + kb, &Blds[cur * 4096 + ldsO[r]]);
      }
    }
    cur ^= 1;
  }
  int col0 = nb + l16;
  int row0 = mb + w * 16 + g * 4;
#pragma unroll
  for (int tn = 0; tn < 4; ++tn) {
    int col = col0 + tn * 16;
#pragma unroll
    for (int r = 0; r < 4; ++r) {
      int row = row0 + r;
      float v = acc[tn][r];
      if (res) v += res[(size_t)row * N + col];
      C[(size_t)row * N + col] = v;
    }
  }
}

// ------- MFMA flash attention: tm=2 (128-row Q tile, 32 rows/wave) -------
// R12-R15: conflicts/occupancy/staging fixes all ~null -> amortize the per-iter
// phase chain instead. Each K/V fragment read now feeds TWO MFMAs; staging,
// addressing and barriers per MFMA halve. gload_lds + counted vmcnt kept (R15).
#define KSW(buf_, row_, ch_) ((buf_)*4096 + (row_)*64 + ((((ch_) ^ ((row_)&7)))*8))
__global__ __launch_bounds__(256, 2) void attn_mfma(const u16* __restrict__ Qt,
                                                    const u16* __restrict__ Kt,
                                                    const f16* __restrict__ Vb,
                                                    f16* __restrict__ Opart,
                                                    float* __restrict__ Lpart) {
  __shared__ __align__(16) u16 Klds[2 * 64 * 64];  // 16 KB
  __shared__ __align__(16) f16 Vlds[2 * 64 * 64];  // 16 KB
  int flat = blockIdx.x;                     // 0..511
  int xcd = flat & 7, idx = flat >> 3;       // idx 0..63
  int h  = xcd * 2 + ((idx >> 4) & 1);       // 2 heads per XCD chunk
  int sp = idx >> 5;
  int ib = (idx & 15) * 128;
  int j0 = sp * JCHUNK;
  int t = threadIdx.x;
  int w = t >> 6, lane = t & 63;
  int g = lane >> 4, l16 = lane & 15;

  bf16x8 bq[2][2];  // [tm][kk]
#pragma unroll
  for (int tm = 0; tm < 2; ++tm) {
    const u16* qb = Qt + (size_t)(ib + w * 32 + tm * 16 + l16) * D_MODEL + h * DHEAD + g * 8;
    bq[tm][0] = *(const bf16x8*)(qb);
    bq[tm][1] = *(const bf16x8*)(qb + 32);
  }

  f32x4 acc_o[2][4];
#pragma unroll
  for (int tm = 0; tm < 2; ++tm)
#pragma unroll
    for (int i = 0; i < 4; ++i) acc_o[tm][i] = (f32x4){0.f, 0.f, 0.f, 0.f};
  f32x4 acc_l[2];
  acc_l[0] = (f32x4){0.f, 0.f, 0.f, 0.f};
  acc_l[1] = (f32x4){0.f, 0.f, 0.f, 0.f};
  f16x4 ones;
  ones[0] = (f16)1.f; ones[1] = (f16)1.f; ones[2] = (f16)1.f; ones[3] = (f16)1.f;

  // staging descriptors: 512 slots of 16B per tile, lane-linear LDS dest,
  // inverse swizzle on global source (physical layout = KSW involution)
  const u16* KgP[2]; const f16* VgP[2]; int ldsS[2];
#pragma unroll
  for (int r = 0; r < 2; ++r) {
    int s = r * 256 + t;               // 0..511
    int row = s >> 3, pch = s & 7;
    int lch = pch ^ (row & 7);
    KgP[r] = Kt + (size_t)(j0 + row) * D_MODEL + h * DHEAD + lch * 8;
    VgP[r] = Vb + (size_t)(h * DHEAD + row) * SEQ_N + j0 + lch * 8;
    ldsS[r] = s * 8;
  }

  // prologue: stage tiles 0 and 1 (8 VMEM ops/thread in flight)
#pragma unroll
  for (int r = 0; r < 2; ++r) { ASYNC16(KgP[r], &Klds[ldsS[r]]); ASYNC16(VgP[r], &Vlds[ldsS[r]]); }
#pragma unroll
  for (int r = 0; r < 2; ++r) {
    ASYNC16(KgP[r] + 64 * D_MODEL, &Klds[4096 + ldsS[r]]);
    ASYNC16(VgP[r] + 64,           &Vlds[4096 + ldsS[r]]);
  }

  int cur = 0;
  for (int it = 0; it < NIT; ++it) {
    if (it < NIT - 1) asm volatile("s_waitcnt vmcnt(4)" ::: "memory");
    else              asm volatile("s_waitcnt vmcnt(0)" ::: "memory");
    __builtin_amdgcn_s_barrier();

    // S^T = K.Q^T : each K fragment feeds 2 MFMAs (tm=0,1)
    f32x4 s[2][4];
#pragma unroll
    for (int tm = 0; tm < 2; ++tm)
#pragma unroll
      for (int i = 0; i < 4; ++i) s[tm][i] = (f32x4){0.f, 0.f, 0.f, 0.f};
    __builtin_amdgcn_s_setprio(1);
#pragma unroll
    for (int kk = 0; kk < 2; ++kk)
#pragma unroll
      for (int tn = 0; tn < 4; ++tn) {
        int row = tn * 16 + l16;
        bf16x8 ak = *(const bf16x8*)(&Klds[KSW(cur, row, kk * 4 + g)]);
#pragma unroll
        for (int tm = 0; tm < 2; ++tm)
          s[tm][tn] = __builtin_amdgcn_mfma_f32_16x16x32_bf16(ak, bq[tm][kk],
                                                              s[tm][tn], 0, 0, 0);
      }
    __builtin_amdgcn_s_setprio(0);
    f16x4 pf[2][4];
#pragma unroll
    for (int tm = 0; tm < 2; ++tm)
#pragma unroll
      for (int tn = 0; tn < 4; ++tn) {
        f16x4 p;
#pragma unroll
        for (int r = 0; r < 4; ++r)
          p[r] = (f16)exp2f(s[tm][tn][r] - EXPOFF);
        pf[tm][tn] = p;
      }
    // O += P.V : each V fragment feeds 2 MFMAs; rowsum via ones-MFMA
    __builtin_amdgcn_s_setprio(1);
#pragma unroll
    for (int tn = 0; tn < 4; ++tn) {
      acc_l[0] = __builtin_amdgcn_mfma_f32_16x16x16f16(pf[0][tn], ones, acc_l[0], 0, 0, 0);
      acc_l[1] = __builtin_amdgcn_mfma_f32_16x16x16f16(pf[1][tn], ones, acc_l[1], 0, 0, 0);
#pragma unroll
      for (int td = 0; td < 4; ++td) {
        int row = td * 16 + l16;
        f16x4 bv = *(const f16x4*)(&Vlds[KSW(cur, row, tn * 2 + (g >> 1)) + (g & 1) * 4]);
#pragma unroll
        for (int tm = 0; tm < 2; ++tm)
          acc_o[tm][td] =
              __builtin_amdgcn_mfma_f32_16x16x16f16(pf[tm][tn], bv, acc_o[tm][td], 0, 0, 0);
      }
    }
    __builtin_amdgcn_s_setprio(0);

    __builtin_amdgcn_s_barrier();   // all waves done reading buf[cur]
    if (it + 2 < NIT) {             // stage tile it+2 into the freed buffer
      int joff = (it + 2) * 64;
#pragma unroll
      for (int r = 0; r < 2; ++r) {
        ASYNC16(KgP[r] + (size_t)joff * D_MODEL, &Klds[cur * 4096 + ldsS[r]]);
        ASYNC16(VgP[r] + joff,                   &Vlds[cur * 4096 + ldsS[r]]);
      }
    }
    cur ^= 1;
  }

  // L partial (acc_l cols identical across l16; one lane per row writes)
  if (l16 == 0) {
#pragma unroll
    for (int tm = 0; tm < 2; ++tm)
#pragma unroll
      for (int r = 0; r < 4; ++r)
        Lpart[((size_t)sp * HEADS + h) * SEQ_N + ib + w * 32 + tm * 16 + g * 4 + r] =
            acc_l[tm][r];
  }

  // O partial (unnormalized, f16)
#pragma unroll
  for (int tm = 0; tm < 2; ++tm)
#pragma unroll
    for (int td = 0; td < 4; ++td) {
      int dh = h * DHEAD + td * 16 + l16;
#pragma unroll
      for (int r = 0; r < 4; ++r) {
        int i = ib + w * 32 + tm * 16 + g * 4 + r;
        Opart[((size_t)sp * SEQ_N + i) * D_MODEL + dh] = (f16)acc_o[tm][td][r];
      }
    }
}

// ---------------- combine splits -> attnt bf16 ----------------
__global__ __launch_bounds__(256) void attn_combine(const f16* __restrict__ Opart,
                                                    const float* __restrict__ Lpart,
                                                    u16* __restrict__ attnt) {
  int i = blockIdx.x;
  int c = threadIdx.x * 4;
  int h = c >> 6;
  float l = 0.f;
#pragma unroll
  for (int s = 0; s < JSPLIT; ++s) l += Lpart[((size_t)s * HEADS + h) * SEQ_N + i];
  float o[4] = {0.f, 0.f, 0.f, 0.f};
#pragma unroll
  for (int s = 0; s < JSPLIT; ++s) {
    f16x4 v = *(const f16x4*)(&Opart[((size_t)s * SEQ_N + i) * D_MODEL + c]);
#pragma unroll
    for (int r = 0; r < 4; ++r) o[r] += (float)v[r];
  }
  float inv = 1.0f / l;
  ushort4 ob;
  ob.x = f2bf(o[0] * inv); ob.y = f2bf(o[1] * inv);
  ob.z = f2bf(o[2] * inv); ob.w = f2bf(o[3] * inv);
  *(ushort4*)(&attnt[(size_t)i * D_MODEL + c]) = ob;
}

// ---------------- launch ----------------
extern "C" void kernel_launch(void* const* d_in, const int* in_sizes, int n_in,
                              void* d_out, int out_size, void* d_ws, size_t ws_size,
                              hipStream_t stream) {
  const float* x  = (const float*)d_in[0];
  const float* WQ = (const float*)d_in[1];
  const float* WK = (const float*)d_in[2];
  const float* WV = (const float*)d_in[3];
  const float* W0 = (const float*)d_in[4];
  float* out = (float*)d_out;

  char* ws = (char*)d_ws;
  size_t off = 0;
  double* part  = (double*)(ws + off); off += 8192;
  u16*    xnt   = (u16*)(ws + off); off += (size_t)SEQ_N * D_MODEL * 2;
  u16*    Wp    = (u16*)(ws + off); off += (size_t)M3 * D_MODEL * 2;
  u16*    W0p   = (u16*)(ws + off); off += (size_t)D_MODEL * D_MODEL * 2;
  u16*    Qt    = (u16*)(ws + off); off += (size_t)SEQ_N * D_MODEL * 2;
  u16*    Kt    = (u16*)(ws + off); off += (size_t)SEQ_N * D_MODEL * 2;
  f16*    Vb    = (f16*)(ws + off); off += (size_t)D_MODEL * SEQ_N * 2;
  u16*    attnt = (u16*)(ws + off); off += (size_t)SEQ_N * D_MODEL * 2;
  f16*    Opart = (f16*)(ws + off); off += (size_t)JSPLIT * SEQ_N * D_MODEL * 2;  // 8 MB
  float*  Lpart = (float*)(ws + off); off += (size_t)JSPLIT * HEADS * SEQ_N * 4;  // 256 KB

  prep<<<256 + 2048, 256, 0, stream>>>(x, part, WQ, WK, WV, W0, Wp, W0p);
  ln_norm_t<<<dim3(SEQ_N / 64, D_MODEL / 64), 256, 0, stream>>>(x, part, xnt);
  gemm_qkv<<<512, 256, 0, stream>>>(Wp, xnt, Qt, Kt, Vb);
  attn_mfma<<<512, 256, 0, stream>>>(Qt, Kt, Vb, Opart, Lpart);
  attn_combine<<<SEQ_N, 256, 0, stream>>>(Opart, Lpart, attnt);
  gemm_bf16<<<512, 256, 0, stream>>>(W0p, attnt, out, x, D_MODEL, SEQ_N, D_MODEL);
}

// Round 17
// 151.006 us; speedup vs baseline: 1.0319x; 1.0319x over previous
//
#include <hip/hip_runtime.h>
#include <math.h>

typedef unsigned short u16;
typedef _Float16 f16;
typedef __attribute__((ext_vector_type(8))) short bf16x8;
typedef __attribute__((ext_vector_type(4))) float f32x4;
typedef __attribute__((ext_vector_type(4))) f16 f16x4;

#define D_MODEL 1024
#define SEQ_N   2048
#define HEADS   16
#define DHEAD   64
#define M3      3072
#define JSPLIT  2
#define JCHUNK  (SEQ_N / JSPLIT)   // 1024
#define NIT     (JCHUNK / 64)      // 16
// Q pre-scale: 0.125 * log2(e); attn then uses exp2(s - 4*log2(e)) == exp(s/8 - 4)
#define QSCALE  0.18033688011112042f
#define EXPOFF  5.770780163555854f

#define GLOBAL_AS __attribute__((address_space(1)))
#define LDS_AS    __attribute__((address_space(3)))
#define ASYNC16(gp, lp) __builtin_amdgcn_global_load_lds( \
    (const GLOBAL_AS unsigned int*)(gp), (LDS_AS unsigned int*)(lp), 16, 0, 0)

__device__ __forceinline__ u16 f2bf(float f) {
  union { float f; unsigned int u; } v; v.f = f;
  unsigned int r = v.u + 0x7fffu + ((v.u >> 16) & 1u);  // RNE
  return (u16)(r >> 16);
}

// ------- prep: blocks [0,256) = LN stage-1 reduce; blocks [256,2304) = weight pack -------
__global__ __launch_bounds__(256) void prep(const float* __restrict__ x,
                                            double* __restrict__ part,
                                            const float* __restrict__ WQ,
                                            const float* __restrict__ WK,
                                            const float* __restrict__ WV,
                                            const float* __restrict__ W0,
                                            u16* __restrict__ Wp,
                                            u16* __restrict__ W0p) {
  __shared__ double ls[256], lss[256];
  __shared__ float tile[32][65];
  int t = threadIdx.x;
  int b = blockIdx.x;
  if (b < 256) {
    const float4* x4 = (const float4*)x;
    const int n4 = (D_MODEL * SEQ_N) / 4;
    double s = 0.0, ss = 0.0;
    for (int idx = b * 256 + t; idx < n4; idx += 256 * 256) {
      float4 v = x4[idx];
      s  += (double)v.x + (double)v.y + (double)v.z + (double)v.w;
      ss += (double)v.x * v.x + (double)v.y * v.y + (double)v.z * v.z + (double)v.w * v.w;
    }
    ls[t] = s; lss[t] = ss;
    __syncthreads();
    for (int off = 128; off > 0; off >>= 1) {
      if (t < off) { ls[t] += ls[t + off]; lss[t] += lss[t + off]; }
      __syncthreads();
    }
    if (t == 0) { part[2 * b] = ls[0]; part[2 * b + 1] = lss[0]; }
    return;
  }
  int f = b - 256;
  int z = f >> 9;
  int rem = f & 511;
  if (z == 3) {
    int idx = rem * 512 + t;
#pragma unroll
    for (int r = 0; r < 2; ++r, idx += 256) {
      float4 v = ((const float4*)W0)[idx];
      unsigned int lo = (unsigned int)f2bf(v.x) | ((unsigned int)f2bf(v.y) << 16);
      unsigned int hi = (unsigned int)f2bf(v.z) | ((unsigned int)f2bf(v.w) << 16);
      uint2 o; o.x = lo; o.y = hi;
      *(uint2*)(&W0p[(size_t)idx * 4]) = o;
    }
    return;
  }
  const float* W = (z == 0) ? WQ : ((z == 1) ? WK : WV);
  int h = rem >> 5, cb = (rem & 31) * 32;
  int dh = t & 63, cl = t >> 6;
  for (int r = 0; r < 8; ++r) {
    int c = cl + r * 4;
    tile[c][dh] = W[((size_t)h * D_MODEL + cb + c) * DHEAD + dh];
  }
  __syncthreads();
  int c2 = t & 31, d2 = t >> 5;
  for (int r = 0; r < 8; ++r) {
    int dd = d2 + r * 8;
    Wp[(size_t)((z * HEADS + h) * DHEAD + dd) * D_MODEL + cb + c2] = f2bf(tile[c2][dd]);
  }
}

// ------- normalize + transpose: x[d,N] -> xn_t[N,d] (bf16); stage-2 reduce fused -------
__global__ __launch_bounds__(256) void ln_norm_t(const float* __restrict__ x,
                                                 const double* __restrict__ part,
                                                 u16* __restrict__ xnt) {
  __shared__ double ls[256], lss[256];
  __shared__ float tile[64][65];
  int t = threadIdx.x;
  ls[t] = part[2 * t]; lss[t] = part[2 * t + 1];
  __syncthreads();
  for (int off = 128; off > 0; off >>= 1) {
    if (t < off) { ls[t] += ls[t + off]; lss[t] += lss[t + off]; }
    __syncthreads();
  }
  double inv = 1.0 / ((double)D_MODEL * (double)SEQ_N);
  double m = ls[0] * inv;
  double vv = lss[0] * inv - m * m;
  float mean = (float)m;
  float rstd = (float)(1.0 / sqrt(vv + 1e-5));

  int ib = blockIdx.x * 64, cb = blockIdx.y * 64;
  int il = t & 63, cl = t >> 6;
  for (int r = 0; r < 16; ++r) {
    int c = cl + r * 4;
    tile[c][il] = (x[(size_t)(cb + c) * SEQ_N + ib + il] - mean) * rstd;
  }
  __syncthreads();
  int c2 = t & 63, i2 = t >> 6;
  for (int r = 0; r < 16; ++r) {
    int i = i2 + r * 4;
    xnt[(size_t)(ib + i) * D_MODEL + cb + c2] = f2bf(tile[c2][i]);
  }
}

// -------- QKV projection GEMM: 96(M)x128(N), BK=64, counted-vmcnt dbuf + T2 swizzle --------
__global__ __launch_bounds__(256) void gemm_qkv(const u16* __restrict__ A,
                                                const u16* __restrict__ Bt,
                                                u16* __restrict__ Qt,
                                                u16* __restrict__ Kt,
                                                f16* __restrict__ Vb) {
  __shared__ __align__(16) u16 Alds[2 * 2 * 96 * 32];
  __shared__ __align__(16) u16 Blds[2 * 2 * 128 * 32];
  int t = threadIdx.x;
  int lane = t & 63, w = t >> 6;
  int g = lane >> 4, l16 = lane & 15;
  int wr = w >> 1, wc = w & 1;
  int flat = blockIdx.x;
  int wi = flat >> 3;
  int wx = wi & 7, wy = wi >> 3;
  int cx = (flat & 7) & 1, cy = (flat & 7) >> 1;
  int bx = cx * 8 + wx;
  int by = cy * 8 + wy;
  int mb = by * 96, nb = bx * 128;

  f32x4 acc[3][4];
#pragma unroll
  for (int i = 0; i < 3; ++i)
#pragma unroll
    for (int j = 0; j < 4; ++j) acc[i][j] = (f32x4){0.f, 0.f, 0.f, 0.f};

  const u16* AgP[3]; int ldsA[3];
#pragma unroll
  for (int r = 0; r < 3; ++r) {
    int idx = r * 256 + t;
    int kk = (idx >= 384) ? 1 : 0;
    int rem = idx - kk * 384;
    int row = rem >> 2, c4 = rem & 3;
    int csw = c4 ^ ((row >> 1) & 3);   // inverse-swizzled source chunk
    AgP[r] = A + (size_t)(mb + row) * D_MODEL + kk * 32 + csw * 8;
    ldsA[r] = idx * 8;                 // LDS dest stays lane-linear
  }
  const u16* BgP[4]; int ldsB[4];
#pragma unroll
  for (int r = 0; r < 4; ++r) {
    int idx = r * 256 + t;
    int kk = idx >> 9;
    int rem = idx & 511;
    int row = rem >> 2, c4 = rem & 3;
    int csw = c4 ^ ((row >> 1) & 3);
    BgP[r] = Bt + (size_t)(nb + row) * D_MODEL + kk * 32 + csw * 8;
    ldsB[r] = idx * 8;
  }

#pragma unroll
  for (int r = 0; r < 3; ++r) ASYNC16(AgP[r], &Alds[ldsA[r]]);
#pragma unroll
  for (int r = 0; r < 4; ++r) ASYNC16(BgP[r], &Blds[ldsB[r]]);
#pragma unroll
  for (int r = 0; r < 3; ++r) ASYNC16(AgP[r] + 64, &Alds[6144 + ldsA[r]]);
#pragma unroll
  for (int r = 0; r < 4; ++r) ASYNC16(BgP[r] + 64, &Blds[8192 + ldsB[r]]);

  int rowa0 = wr * 48, rowb0 = wc * 64;
  int cur = 0;
  for (int ks = 0; ks < 16; ++ks) {
    if (ks < 15) asm volatile("s_waitcnt vmcnt(7)" ::: "memory");
    else         asm volatile("s_waitcnt vmcnt(0)" ::: "memory");
    __builtin_amdgcn_s_barrier();
#pragma unroll
    for (int kk = 0; kk < 2; ++kk) {
      bf16x8 af[3], bf[4];
#pragma unroll
      for (int tm = 0; tm < 3; ++tm) {
        int row = rowa0 + tm * 16 + l16;
        int gs = g ^ ((row >> 1) & 3);   // swizzled read chunk
        af[tm] = *(const bf16x8*)(&Alds[cur * 6144 + kk * 3072 + row * 32 + gs * 8]);
      }
#pragma unroll
      for (int tn = 0; tn < 4; ++tn) {
        int row = rowb0 + tn * 16 + l16;
        int gs = g ^ ((row >> 1) & 3);
        bf[tn] = *(const bf16x8*)(&Blds[cur * 8192 + kk * 4096 + row * 32 + gs * 8]);
      }
#pragma unroll
      for (int tm = 0; tm < 3; ++tm)
#pragma unroll
        for (int tn = 0; tn < 4; ++tn)
          acc[tm][tn] = __builtin_amdgcn_mfma_f32_16x16x32_bf16(af[tm], bf[tn],
                                                                acc[tm][tn], 0, 0, 0);
    }
    __builtin_amdgcn_s_barrier();
    if (ks + 2 < 16) {
      int kb = (ks + 2) * 64;
#pragma unroll
      for (int r = 0; r < 3; ++r) ASYNC16(AgP[r] + kb, &Alds[cur * 6144 + ldsA[r]]);
#pragma unroll
      for (int r = 0; r < 4; ++r) ASYNC16(BgP[r] + kb, &Blds[cur * 8192 + ldsB[r]]);
    }
    cur ^= 1;
  }

#pragma unroll
  for (int tm = 0; tm < 3; ++tm) {
    int row0 = mb + wr * 48 + tm * 16 + g * 4;
#pragma unroll
    for (int tn = 0; tn < 4; ++tn) {
      int col = nb + wc * 64 + tn * 16 + l16;
      if (row0 < 2 * D_MODEL) {
        u16* T = (row0 < D_MODEL) ? Qt : Kt;
        float sc = (row0 < D_MODEL) ? QSCALE : 1.0f;  // pre-scale Q only
        int rbase = (row0 < D_MODEL) ? row0 : row0 - D_MODEL;
        ushort4 o;
        o.x = f2bf(acc[tm][tn][0] * sc); o.y = f2bf(acc[tm][tn][1] * sc);
        o.z = f2bf(acc[tm][tn][2] * sc); o.w = f2bf(acc[tm][tn][3] * sc);
        *(ushort4*)(&T[(size_t)col * D_MODEL + rbase]) = o;
      } else {
        int rbase = row0 - 2 * D_MODEL;
#pragma unroll
        for (int r = 0; r < 4; ++r)
          Vb[(size_t)(rbase + r) * SEQ_N + col] = (f16)acc[tm][tn][r];
      }
    }
  }
}

// ------- out-proj GEMM 64x64, BK=64, counted-vmcnt dbuf + T2 swizzle -------
__global__ __launch_bounds__(256) void gemm_bf16(const u16* __restrict__ A,
                                                 const u16* __restrict__ Bt,
                                                 float* __restrict__ C,
                                                 const float* __restrict__ res,
                                                 int M, int N, int K) {
  __shared__ __align__(16) u16 Alds[2 * 2 * 64 * 32];
  __shared__ __align__(16) u16 Blds[2 * 2 * 64 * 32];
  int t = threadIdx.x;
  int w = t >> 6, lane = t & 63;
  int g = lane >> 4, l16 = lane & 15;
  int flat = blockIdx.x;
  int wi = flat >> 3;
  int wx = wi & 7, wy = wi >> 3;
  int cx = (flat & 7) & 3, cy = (flat & 7) >> 2;
  int bx = cx * 8 + wx;
  int by = cy * 8 + wy;
  int mb = by * 64, nb = bx * 64;
  f32x4 acc[4];
  for (int i = 0; i < 4; ++i) acc[i] = (f32x4){0.f, 0.f, 0.f, 0.f};

  const u16* AgP[2]; const u16* BgP[2]; int ldsO[2];
#pragma unroll
  for (int r = 0; r < 2; ++r) {
    int idx = r * 256 + t;
    int kk = idx >> 8;
    int rem = idx & 255;
    int row = rem >> 2, c4 = rem & 3;
    int csw = c4 ^ ((row >> 1) & 3);
    AgP[r] = A + (size_t)(mb + row) * K + kk * 32 + csw * 8;
    BgP[r] = Bt + (size_t)(nb + row) * K + kk * 32 + csw * 8;
    ldsO[r] = idx * 8;
  }

#pragma unroll
  for (int r = 0; r < 2; ++r) { ASYNC16(AgP[r], &Alds[ldsO[r]]); ASYNC16(BgP[r], &Blds[ldsO[r]]); }
#pragma unroll
  for (int r = 0; r < 2; ++r) {
    ASYNC16(AgP[r] + 64, &Alds[4096 + ldsO[r]]);
    ASYNC16(BgP[r] + 64, &Blds[4096 + ldsO[r]]);
  }

  int cur = 0;
  const int NK = 16;
  for (int ks = 0; ks < NK; ++ks) {
    if (ks < NK - 1) asm volatile("s_waitcnt vmcnt(4)" ::: "memory");
    else             asm volatile("s_waitcnt vmcnt(0)" ::: "memory");
    __builtin_amdgcn_s_barrier();
#pragma unroll
    for (int kk = 0; kk < 2; ++kk) {
      int rowa = w * 16 + l16;
      int gsa = g ^ ((rowa >> 1) & 3);
      bf16x8 af = *(const bf16x8*)(&Alds[cur * 4096 + kk * 2048 + rowa * 32 + gsa * 8]);
#pragma unroll
      for (int tn = 0; tn < 4; ++tn) {
        int rowb = tn * 16 + l16;
        int gsb = g ^ ((rowb >> 1) & 3);
        bf16x8 bf = *(const bf16x8*)(&Blds[cur * 4096 + kk * 2048 + rowb * 32 + gsb * 8]);
        acc[tn] = __builtin_amdgcn_mfma_f32_16x16x32_bf16(af, bf, acc[tn], 0, 0, 0);
      }
    }
    __builtin_amdgcn_s_barrier();
    if (ks + 2 < NK) {
      int kb = (ks + 2) * 64;
#pragma unroll
      for (int r = 0; r < 2; ++r) {
        ASYNC16(AgP[r] + kb, &Alds[cur * 4096 + ldsO[r]]);
        ASYNC16(BgP[r] + kb, &Blds[cur * 4096 + ldsO[r]]);
      }
    }
    cur ^= 1;
  }
  int col0 = nb + l16;
  int row0 = mb + w * 16 + g * 4;
#pragma unroll
  for (int tn = 0; tn < 4; ++tn) {
    int col = col0 + tn * 16;
#pragma unroll
    for (int r = 0; r < 4; ++r) {
      int row = row0 + r;
      float v = acc[tn][r];
      if (res) v += res[(size_t)row * N + col];
      C[(size_t)row * N + col] = v;
    }
  }
}

// ------- MFMA flash attention: global_load_lds staging + counted vmcnt (GEMM structure) -------
// Best-measured configuration (R15, 151.9us). LDS dest lane-linear (slot s=r*256+t,
// row=s>>3, phys chunk=s&7), INVERSE swizzle on global source (lch = pch ^ (row&7));
// reads use the KSW involution. Loop: vmcnt(4) -> barrier -> compute -> barrier ->
// stage tile it+2 into freed buffer.
#define KSW(buf_, row_, ch_) ((buf_)*4096 + (row_)*64 + ((((ch_) ^ ((row_)&7)))*8))
__global__ __launch_bounds__(256, 2) void attn_mfma(const u16* __restrict__ Qt,
                                                    const u16* __restrict__ Kt,
                                                    const f16* __restrict__ Vb,
                                                    f16* __restrict__ Opart,
                                                    float* __restrict__ Lpart) {
  __shared__ __align__(16) u16 Klds[2 * 64 * 64];  // 16 KB
  __shared__ __align__(16) f16 Vlds[2 * 64 * 64];  // 16 KB
  int flat = blockIdx.x;                     // 0..1023
  int xcd = flat & 7, idx = flat >> 3;       // idx 0..127
  int h  = xcd * 2 + ((idx >> 5) & 1);       // both j-splits of a head stay on one XCD
  int sp = idx >> 6;
  int ib = (idx & 31) * 64;
  int j0 = sp * JCHUNK;
  int t = threadIdx.x;
  int w = t >> 6, lane = t & 63;
  int g = lane >> 4, l16 = lane & 15;

  bf16x8 bq[2];
  {
    const u16* qb = Qt + (size_t)(ib + w * 16 + l16) * D_MODEL + h * DHEAD + g * 8;
    bq[0] = *(const bf16x8*)(qb);
    bq[1] = *(const bf16x8*)(qb + 32);
  }

  f32x4 acc_o[4];
#pragma unroll
  for (int i = 0; i < 4; ++i) acc_o[i] = (f32x4){0.f, 0.f, 0.f, 0.f};
  f32x4 acc_l = (f32x4){0.f, 0.f, 0.f, 0.f};
  f16x4 ones;
  ones[0] = (f16)1.f; ones[1] = (f16)1.f; ones[2] = (f16)1.f; ones[3] = (f16)1.f;

  // staging descriptors: 512 slots of 16B per tile, lane-linear LDS dest
  const u16* KgP[2]; const f16* VgP[2]; int ldsS[2];
#pragma unroll
  for (int r = 0; r < 2; ++r) {
    int s = r * 256 + t;               // 0..511
    int row = s >> 3, pch = s & 7;
    int lch = pch ^ (row & 7);         // inverse-swizzled source chunk
    KgP[r] = Kt + (size_t)(j0 + row) * D_MODEL + h * DHEAD + lch * 8;
    VgP[r] = Vb + (size_t)(h * DHEAD + row) * SEQ_N + j0 + lch * 8;
    ldsS[r] = s * 8;                   // linear u16 offset within tile buffer
  }

  // prologue: stage tiles 0 and 1 (8 VMEM ops/thread in flight)
#pragma unroll
  for (int r = 0; r < 2; ++r) { ASYNC16(KgP[r], &Klds[ldsS[r]]); ASYNC16(VgP[r], &Vlds[ldsS[r]]); }
#pragma unroll
  for (int r = 0; r < 2; ++r) {
    ASYNC16(KgP[r] + 64 * D_MODEL, &Klds[4096 + ldsS[r]]);
    ASYNC16(VgP[r] + 64,           &Vlds[4096 + ldsS[r]]);
  }

  int cur = 0;
  for (int it = 0; it < NIT; ++it) {
    if (it < NIT - 1) asm volatile("s_waitcnt vmcnt(4)" ::: "memory");
    else              asm volatile("s_waitcnt vmcnt(0)" ::: "memory");
    __builtin_amdgcn_s_barrier();

    // S^T = K.Q^T
    f32x4 s[4];
#pragma unroll
    for (int i = 0; i < 4; ++i) s[i] = (f32x4){0.f, 0.f, 0.f, 0.f};
    __builtin_amdgcn_s_setprio(1);
#pragma unroll
    for (int kk = 0; kk < 2; ++kk)
#pragma unroll
      for (int tn = 0; tn < 4; ++tn) {
        int row = tn * 16 + l16;
        bf16x8 ak = *(const bf16x8*)(&Klds[KSW(cur, row, kk * 4 + g)]);
        s[tn] = __builtin_amdgcn_mfma_f32_16x16x32_bf16(ak, bq[kk], s[tn], 0, 0, 0);
      }
    __builtin_amdgcn_s_setprio(0);
    f16x4 pf[4];
#pragma unroll
    for (int tn = 0; tn < 4; ++tn) {
      f16x4 p;
#pragma unroll
      for (int r = 0; r < 4; ++r)
        p[r] = (f16)exp2f(s[tn][r] - EXPOFF);
      pf[tn] = p;
    }
    __builtin_amdgcn_s_setprio(1);
#pragma unroll
    for (int tn = 0; tn < 4; ++tn) {
      acc_l = __builtin_amdgcn_mfma_f32_16x16x16f16(pf[tn], ones, acc_l, 0, 0, 0);
#pragma unroll
      for (int td = 0; td < 4; ++td) {
        int row = td * 16 + l16;
        f16x4 bv = *(const f16x4*)(&Vlds[KSW(cur, row, tn * 2 + (g >> 1)) + (g & 1) * 4]);
        acc_o[td] =
            __builtin_amdgcn_mfma_f32_16x16x16f16(pf[tn], bv, acc_o[td], 0, 0, 0);
      }
    }
    __builtin_amdgcn_s_setprio(0);

    __builtin_amdgcn_s_barrier();   // all waves done reading buf[cur]
    if (it + 2 < NIT) {             // stage tile it+2 into the freed buffer
      int joff = (it + 2) * 64;
#pragma unroll
      for (int r = 0; r < 2; ++r) {
        ASYNC16(KgP[r] + (size_t)joff * D_MODEL, &Klds[cur * 4096 + ldsS[r]]);
        ASYNC16(VgP[r] + joff,                   &Vlds[cur * 4096 + ldsS[r]]);
      }
    }
    cur ^= 1;
  }

  // L partial (acc_l cols identical across l16; one lane per row writes)
  if (l16 == 0) {
#pragma unroll
    for (int r = 0; r < 4; ++r)
      Lpart[((size_t)sp * HEADS + h) * SEQ_N + ib + w * 16 + g * 4 + r] = acc_l[r];
  }

  // O partial (unnormalized, f16)
#pragma unroll
  for (int td = 0; td < 4; ++td) {
    int dh = h * DHEAD + td * 16 + l16;
#pragma unroll
    for (int r = 0; r < 4; ++r) {
      int i = ib + w * 16 + g * 4 + r;
      Opart[((size_t)sp * SEQ_N + i) * D_MODEL + dh] = (f16)acc_o[td][r];
    }
  }
}

// ---------------- combine splits -> attnt bf16 ----------------
__global__ __launch_bounds__(256) void attn_combine(const f16* __restrict__ Opart,
                                                    const float* __restrict__ Lpart,
                                                    u16* __restrict__ attnt) {
  int i = blockIdx.x;
  int c = threadIdx.x * 4;
  int h = c >> 6;
  float l = 0.f;
#pragma unroll
  for (int s = 0; s < JSPLIT; ++s) l += Lpart[((size_t)s * HEADS + h) * SEQ_N + i];
  float o[4] = {0.f, 0.f, 0.f, 0.f};
#pragma unroll
  for (int s = 0; s < JSPLIT; ++s) {
    f16x4 v = *(const f16x4*)(&Opart[((size_t)s * SEQ_N + i) * D_MODEL + c]);
#pragma unroll
    for (int r = 0; r < 4; ++r) o[r] += (float)v[r];
  }
  float inv = 1.0f / l;
  ushort4 ob;
  ob.x = f2bf(o[0] * inv); ob.y = f2bf(o[1] * inv);
  ob.z = f2bf(o[2] * inv); ob.w = f2bf(o[3] * inv);
  *(ushort4*)(&attnt[(size_t)i * D_MODEL + c]) = ob;
}

// ---------------- launch ----------------
extern "C" void kernel_launch(void* const* d_in, const int* in_sizes, int n_in,
                              void* d_out, int out_size, void* d_ws, size_t ws_size,
                              hipStream_t stream) {
  const float* x  = (const float*)d_in[0];
  const float* WQ = (const float*)d_in[1];
  const float* WK = (const float*)d_in[2];
  const float* WV = (const float*)d_in[3];
  const float* W0 = (const float*)d_in[4];
  float* out = (float*)d_out;

  char* ws = (char*)d_ws;
  size_t off = 0;
  double* part  = (double*)(ws + off); off += 8192;
  u16*    xnt   = (u16*)(ws + off); off += (size_t)SEQ_N * D_MODEL * 2;
  u16*    Wp    = (u16*)(ws + off); off += (size_t)M3 * D_MODEL * 2;
  u16*    W0p   = (u16*)(ws + off); off += (size_t)D_MODEL * D_MODEL * 2;
  u16*    Qt    = (u16*)(ws + off); off += (size_t)SEQ_N * D_MODEL * 2;
  u16*    Kt    = (u16*)(ws + off); off += (size_t)SEQ_N * D_MODEL * 2;
  f16*    Vb    = (f16*)(ws + off); off += (size_t)D_MODEL * SEQ_N * 2;
  u16*    attnt = (u16*)(ws + off); off += (size_t)SEQ_N * D_MODEL * 2;
  f16*    Opart = (f16*)(ws + off); off += (size_t)JSPLIT * SEQ_N * D_MODEL * 2;  // 8 MB
  float*  Lpart = (float*)(ws + off); off += (size_t)JSPLIT * HEADS * SEQ_N * 4;  // 256 KB

  prep<<<256 + 2048, 256, 0, stream>>>(x, part, WQ, WK, WV, W0, Wp, W0p);
  ln_norm_t<<<dim3(SEQ_N / 64, D_MODEL / 64), 256, 0, stream>>>(x, part, xnt);
  gemm_qkv<<<512, 256, 0, stream>>>(Wp, xnt, Qt, Kt, Vb);
  attn_mfma<<<1024, 256, 0, stream>>>(Qt, Kt, Vb, Opart, Lpart);
  attn_combine<<<SEQ_N, 256, 0, stream>>>(Opart, Lpart, attnt);
  gemm_bf16<<<512, 256, 0, stream>>>(W0p, attnt, out, x, D_MODEL, SEQ_N, D_MODEL);
}